// Round 8
// baseline (798.044 us; speedup 1.0000x reference)
//
#include <hip/hip_runtime.h>
#include <hip/hip_cooperative_groups.h>
#include <math.h>

namespace cg = cooperative_groups;

#define NNODES 50000
#define FIN 512
#define HID 64
#define HEADS 4
#define HD (HEADS * HID)   // 256
#define NCLS 40
#define NCLSP 64           // padded to 4x16 MFMA n-tiles; pow2 for 8-lane-per-edge agg2
#define NEG_SLOPE 0.2f
#define SBLK 256
#define NSCAN ((NNODES + SBLK - 1) / SBLK)   // 196

typedef __attribute__((ext_vector_type(8))) short short8;
typedef __attribute__((ext_vector_type(4))) float f32x4;

static __device__ inline unsigned short f2bf(float f) {
    unsigned int u = __builtin_bit_cast(unsigned int, f);
    unsigned int r = (u + 0x7FFFu + ((u >> 16) & 1u)) >> 16;
    return (unsigned short)r;
}
static __device__ inline float bf2f(unsigned short b) {
    return __builtin_bit_cast(float, (unsigned int)b << 16);
}
static __device__ inline void gload_lds16(const void* g, void* l) {
    __builtin_amdgcn_global_load_lds(
        (const __attribute__((address_space(1))) unsigned int*)g,
        (__attribute__((address_space(3))) unsigned int*)l, 16, 0, 0);
}

// ---------------- cooperative CSR build + weight transposes ------------------
// One kernel replaces {memset, pre, scan1, scan23, scatter}: phases separated
// by grid.sync(). 960 blocks x 256 threads (co-resident: 4 waves/block, tiny
// VGPR/LDS -> well under 8 blocks/CU).
__global__ __launch_bounds__(256) void csr_kernel(const int* __restrict__ ei, int E,
                                                  const float* __restrict__ W1,
                                                  unsigned short* __restrict__ W1t,
                                                  const float* __restrict__ W2,
                                                  unsigned short* __restrict__ W2t,
                                                  int* __restrict__ deg,
                                                  int* __restrict__ cursor,
                                                  int* __restrict__ psum,
                                                  int* __restrict__ bsum,
                                                  int* __restrict__ offs,
                                                  int* __restrict__ csr_src) {
    cg::grid_group grid = cg::this_grid();
    const int tid = threadIdx.x;
    const int gidx = blockIdx.x * 256 + tid;
    const int gstride = gridDim.x * 256;
    __shared__ int ws[4];
    __shared__ int sc[NSCAN];

    // ---- phase A: zero deg/cursor, csr pad, W transposes (all independent) --
    for (int i = gidx; i < NNODES; i += gstride) { deg[i] = 0; cursor[i] = 0; }
    if (gidx < 64) csr_src[E + gidx] = 0;        // safe pad for clamp-free aggs
    for (int i = gidx; i < FIN * HD; i += gstride) {
        const int k = i >> 8;                    // 0..511
        const int n = i & 255;                   // 0..255
        W1t[n * FIN + k] = f2bf(W1[i]);
    }
    for (int i = gidx; i < NCLSP * HD; i += gstride) {
        const int n = i >> 8;                    // 0..63
        const int k = i & 255;                   // 0..255
        W2t[n * HD + k] = (n < NCLS) ? f2bf(W2[k * NCLS + n]) : (unsigned short)0;
    }
    grid.sync();

    // ---- phase B: degree count ---------------------------------------------
    for (int e = gidx; e < E; e += gstride) atomicAdd(&deg[ei[E + e]], 1);
    grid.sync();

    // ---- phase C: per-block inclusive scan (blocks 0..NSCAN-1) -------------
    if (blockIdx.x < NSCAN) {
        const int idx = blockIdx.x * SBLK + tid;
        const int lane = tid & 63;
        const int w = tid >> 6;
        int sv = (idx < NNODES) ? deg[idx] : 0;
        #pragma unroll
        for (int off = 1; off < 64; off <<= 1) {
            const int n = __shfl_up(sv, off);
            if (lane >= off) sv += n;
        }
        if (lane == 63) ws[w] = sv;
        __syncthreads();
        int add = 0;
        for (int i = 0; i < w; ++i) add += ws[i];
        sv += add;
        if (idx < NNODES) psum[idx] = sv;
        if (tid == SBLK - 1) bsum[blockIdx.x] = sv;
    }
    grid.sync();

    // ---- phase D: block-sum scan (redundant per block) + offsets -----------
    if (blockIdx.x < NSCAN) {
        __syncthreads();                         // ws reuse fence from phase C
        const int lane = tid & 63;
        const int w = tid >> 6;
        int sv = (tid < NSCAN) ? bsum[tid] : 0;
        #pragma unroll
        for (int off = 1; off < 64; off <<= 1) {
            const int n = __shfl_up(sv, off);
            if (lane >= off) sv += n;
        }
        if (lane == 63) ws[w] = sv;
        __syncthreads();
        int add = 0;
        for (int i = 0; i < w; ++i) add += ws[i];
        sv += add;
        if (tid < NSCAN) sc[tid] = sv;
        __syncthreads();
        const int idx = blockIdx.x * SBLK + tid;
        const int boff = (blockIdx.x > 0) ? sc[blockIdx.x - 1] : 0;
        if (idx < NNODES) offs[idx] = psum[idx] - deg[idx] + boff;
        if (blockIdx.x == 0 && tid == 0) offs[NNODES] = sc[NSCAN - 1];
    }
    grid.sync();

    // ---- phase E: scatter ---------------------------------------------------
    for (int e = gidx; e < E; e += gstride) {
        const int dst = ei[E + e];
        const int src = ei[e];
        const int pos = offs[dst] + atomicAdd(&cursor[dst], 1);
        csr_src[pos] = src;
    }
}

// ---------------- GEMM1: BM=64 BN=256 BK=32, all-DMA staging (R6) ------------
#define BM 64
#define BN 256
#define BK 32
#define G1BLK ((NNODES + BM - 1) / BM)   // 782

__global__ __launch_bounds__(256) void gemm1_kernel(const float* __restrict__ x,
                                                    const unsigned short* __restrict__ W1t,
                                                    const float* __restrict__ a_src,
                                                    const float* __restrict__ a_dst,
                                                    unsigned short* __restrict__ h1,
                                                    float* __restrict__ al_s,
                                                    float* __restrict__ al_d) {
    __shared__ float As32[2][BM * BK];         // 2 x 8 KB  [row][32 fp32] (swizzled chunks)
    __shared__ unsigned short Bs[2][BN * BK];  // 2 x 16 KB [n][k] bf16
    const int tid = threadIdx.x;
    const int wave = tid >> 6;
    const int lane = tid & 63;
    const int quad = lane >> 4;
    const int col = lane & 15;
    const int m0 = blockIdx.x * BM;
    const int srow = lane >> 2;          // 0..15 within a 16-row group
    const int skk = (lane & 3) * 8;      // 8-elem bf16 (16B) k-chunk
    const int l3 = lane >> 3;            // row within 8-row group
    const int ch = lane & 7;             // stored 16B chunk within 128B row
    const int chs = ch ^ l3;             // swizzled source chunk (row&7 == l3)

    f32x4 acc[4][4] = {};

    auto stageA = [&](int buf, int k0) {
        #pragma unroll
        for (int j = 0; j < 2; ++j) {
            const int row = wave * 16 + j * 8 + l3;
            const size_t rg = (size_t)min(m0 + row, NNODES - 1) * FIN;  // clamped
            gload_lds16(&x[rg + k0 + chs * 4], &As32[buf][row * BK + ch * 4]);
        }
    };
    auto stageB = [&](int buf, int k0) {
        #pragma unroll
        for (int c = 0; c < 4; ++c) {
            const int rr = c * 64 + wave * 16 + srow;
            gload_lds16(&W1t[(size_t)rr * FIN + k0 + skk], &Bs[buf][rr * BK + skk]);
        }
    };
    auto compute = [&](int buf) {
        const int r7 = col & 7;          // (i*16+col)&7 for all i
        short8 af[4], bfv[4];
        #pragma unroll
        for (int i = 0; i < 4; ++i) {
            const int row = i * 16 + col;
            const float4 f0 = *(const float4*)&As32[buf][row * BK + (((2 * quad)     ^ r7) << 2)];
            const float4 f1 = *(const float4*)&As32[buf][row * BK + (((2 * quad + 1) ^ r7) << 2)];
            short8 p;
            p[0] = (short)f2bf(f0.x); p[1] = (short)f2bf(f0.y);
            p[2] = (short)f2bf(f0.z); p[3] = (short)f2bf(f0.w);
            p[4] = (short)f2bf(f1.x); p[5] = (short)f2bf(f1.y);
            p[6] = (short)f2bf(f1.z); p[7] = (short)f2bf(f1.w);
            af[i] = p;
        }
        #pragma unroll
        for (int j = 0; j < 4; ++j)
            bfv[j] = *(const short8*)&Bs[buf][(wave * 64 + j * 16 + col) * BK + quad * 8];
        #pragma unroll
        for (int i = 0; i < 4; ++i)
            #pragma unroll
            for (int j = 0; j < 4; ++j)
                acc[i][j] = __builtin_amdgcn_mfma_f32_16x16x32_bf16(af[i], bfv[j], acc[i][j], 0, 0, 0);
    };

    stageA(0, 0);
    stageB(0, 0);
    __syncthreads();
    int cur = 0;
    for (int k0 = BK; k0 < FIN; k0 += BK) {
        stageA(cur ^ 1, k0);   // async DMAs fly under compute, drain at barrier
        stageB(cur ^ 1, k0);
        compute(cur);
        __syncthreads();
        cur ^= 1;
    }
    compute(cur);

    // epilogue: h1 write + fused per-head attention score dots (head == wave)
    float asv[4], adv[4];
    #pragma unroll
    for (int j = 0; j < 4; ++j) {
        asv[j] = a_src[wave * 64 + j * 16 + col];
        adv[j] = a_dst[wave * 64 + j * 16 + col];
    }
    #pragma unroll
    for (int i = 0; i < 4; ++i) {
        #pragma unroll
        for (int reg = 0; reg < 4; ++reg) {
            const int row = i * 16 + quad * 4 + reg;
            const int gm = m0 + row;
            float ds = 0.f, dd = 0.f;
            #pragma unroll
            for (int j = 0; j < 4; ++j) {
                const float v = acc[i][j][reg];
                ds = fmaf(v, asv[j], ds);
                dd = fmaf(v, adv[j], dd);
                if (gm < NNODES) {
                    const int gc = wave * 64 + j * 16 + col;
                    h1[(size_t)gm * HD + gc] = f2bf(v);
                }
            }
            #pragma unroll
            for (int off = 1; off < 16; off <<= 1) {
                ds += __shfl_xor(ds, off);
                dd += __shfl_xor(dd, off);
            }
            if (col == 0 && gm < NNODES) {
                al_s[gm * HEADS + wave] = ds;
                al_d[gm * HEADS + wave] = dd;
            }
        }
    }
}

// ---------------- layer-1 aggregation: quarter-wave-per-edge, 4 streams ------
// (reverted to the R6 form: 75.4 us known-good; R7's slicing refuted)
__global__ __launch_bounds__(256) void agg1_kernel(const unsigned short* __restrict__ h1,
                                                   const float* __restrict__ al_s,
                                                   const float* __restrict__ al_d,
                                                   const int* __restrict__ offsets,
                                                   const int* __restrict__ csr_src,
                                                   const float* __restrict__ b1,
                                                   unsigned short* __restrict__ h_act) {
    const int node = (blockIdx.x * 256 + threadIdx.x) >> 6;
    const int lane = threadIdx.x & 63;
    const int q = lane >> 4;         // edge stream 0..3
    const int fl = lane & 15;        // feature group: feats fl*16 .. fl*16+15
    const int h = fl >> 2;           // head for this feature group
    const float ad = al_d[node * HEADS + h];
    const int start = offsets[node];
    const int end = offsets[node + 1];

    float s = 0.f;
    float acc[16] = {};

    {
        const int idx = start + q;
        const int src0 = csr_src[idx];
        float sc = (idx < end) ? al_s[src0 * HEADS + h] : -__builtin_inff();
        uint4 v0 = *(const uint4*)&h1[(size_t)src0 * HD + fl * 16];
        uint4 v1 = *(const uint4*)&h1[(size_t)src0 * HD + fl * 16 + 8];

        for (int i = start; i < end; i += 4) {
            const int j = i + 4 + q;
            const int nsrc = csr_src[j];
            const float nsc = (j < end) ? al_s[nsrc * HEADS + h] : -__builtin_inff();
            const uint4 nv0 = *(const uint4*)&h1[(size_t)nsrc * HD + fl * 16];
            const uint4 nv1 = *(const uint4*)&h1[(size_t)nsrc * HD + fl * 16 + 8];
            float e_ = sc + ad;
            e_ = e_ > 0.f ? e_ : NEG_SLOPE * e_;
            const float p = __expf(e_);
            s += p;
            const unsigned int w[8] = {v0.x, v0.y, v0.z, v0.w, v1.x, v1.y, v1.z, v1.w};
            #pragma unroll
            for (int d = 0; d < 8; ++d) {
                const float lo = __builtin_bit_cast(float, w[d] << 16);
                const float hi = __builtin_bit_cast(float, w[d] & 0xFFFF0000u);
                acc[2 * d]     = fmaf(p, lo, acc[2 * d]);
                acc[2 * d + 1] = fmaf(p, hi, acc[2 * d + 1]);
            }
            sc = nsc; v0 = nv0; v1 = nv1;
        }
    }
    s += __shfl_xor(s, 16);
    s += __shfl_xor(s, 32);
    #pragma unroll
    for (int k = 0; k < 16; ++k) {
        acc[k] += __shfl_xor(acc[k], 16);
        acc[k] += __shfl_xor(acc[k], 32);
    }

    if (q == 0) {
        const float inv = 1.f / (s + 1e-16f);
        float bb[16];
        *(float4*)&bb[0]  = *(const float4*)&b1[fl * 16];
        *(float4*)&bb[4]  = *(const float4*)&b1[fl * 16 + 4];
        *(float4*)&bb[8]  = *(const float4*)&b1[fl * 16 + 8];
        *(float4*)&bb[12] = *(const float4*)&b1[fl * 16 + 12];
        short8 ob0, ob1;
        #pragma unroll
        for (int k = 0; k < 8; ++k) {
            const float o0 = acc[k] * inv + bb[k];
            const float o1 = acc[8 + k] * inv + bb[8 + k];
            const float e0 = o0 > 0.f ? o0 : expm1f(o0);
            const float e1 = o1 > 0.f ? o1 : expm1f(o1);
            ob0[k] = (short)f2bf(e0);
            ob1[k] = (short)f2bf(e1);
        }
        *(short8*)&h_act[(size_t)node * HD + fl * 16] = ob0;
        *(short8*)&h_act[(size_t)node * HD + fl * 16 + 8] = ob1;
    }
}

// ---------------- GEMM2 via MFMA: h2[N,64] = h_act[N,256] @ W2pad + dots -----
#define G2M 64
#define BSTRIDE 264

__global__ __launch_bounds__(256) void gemm2_kernel(const unsigned short* __restrict__ h_act,
                                                    const unsigned short* __restrict__ W2t,
                                                    const float* __restrict__ a_s2,
                                                    const float* __restrict__ a_d2,
                                                    unsigned short* __restrict__ h2,
                                                    float* __restrict__ al_s,
                                                    float* __restrict__ al_d) {
    __shared__ unsigned short Bt[NCLSP][BSTRIDE];
    const int tid = threadIdx.x;
    const int wave = tid >> 6;
    const int lane = tid & 63;
    const int quad = lane >> 4;
    const int col = lane & 15;
    const int m0 = blockIdx.x * G2M;

    #pragma unroll
    for (int it = 0; it < 8; ++it) {
        const int ch = it * 256 + tid;
        const int n = ch >> 5;
        const int c8 = (ch & 31) * 8;
        *(uint4*)&Bt[n][c8] = *(const uint4*)&W2t[(size_t)n * HD + c8];
    }

    const int rowm = m0 + wave * 16 + col;
    const int arow = min(rowm, NNODES - 1);
    short8 af[8];
    #pragma unroll
    for (int ks = 0; ks < 8; ++ks)
        af[ks] = *(const short8*)&h_act[(size_t)arow * HD + ks * 32 + quad * 8];

    __syncthreads();

    f32x4 acc[4] = {};
    #pragma unroll
    for (int j = 0; j < 4; ++j) {
        #pragma unroll
        for (int ks = 0; ks < 8; ++ks) {
            const short8 bfr = *(const short8*)&Bt[j * 16 + col][ks * 32 + quad * 8];
            acc[j] = __builtin_amdgcn_mfma_f32_16x16x32_bf16(af[ks], bfr, acc[j], 0, 0, 0);
        }
    }

    float ps[4] = {0.f, 0.f, 0.f, 0.f};
    float pd[4] = {0.f, 0.f, 0.f, 0.f};
    #pragma unroll
    for (int j = 0; j < 4; ++j) {
        const int c = j * 16 + col;
        const bool cv = c < NCLS;
        const float asc = cv ? a_s2[c] : 0.f;
        const float adc = cv ? a_d2[c] : 0.f;
        #pragma unroll
        for (int reg = 0; reg < 4; ++reg) {
            const float v = acc[j][reg];
            ps[reg] += v * asc;
            pd[reg] += v * adc;
            const int node = m0 + wave * 16 + quad * 4 + reg;
            if (node < NNODES)
                h2[(size_t)node * NCLSP + c] = f2bf(v);
        }
    }
    #pragma unroll
    for (int reg = 0; reg < 4; ++reg) {
        #pragma unroll
        for (int off = 1; off < 16; off <<= 1) {
            ps[reg] += __shfl_xor(ps[reg], off);
            pd[reg] += __shfl_xor(pd[reg], off);
        }
    }
    if (col == 0) {
        #pragma unroll
        for (int reg = 0; reg < 4; ++reg) {
            const int node = m0 + wave * 16 + quad * 4 + reg;
            if (node < NNODES) {
                al_s[node] = ps[reg];
                al_d[node] = pd[reg];
            }
        }
    }
}

// ---------------- layer-2 aggregation: octet-per-edge, 8 streams -------------
__global__ __launch_bounds__(256) void agg2_kernel(const unsigned short* __restrict__ h2,
                                                   const float* __restrict__ al_s,
                                                   const float* __restrict__ al_d,
                                                   const int* __restrict__ offsets,
                                                   const int* __restrict__ csr_src,
                                                   const float* __restrict__ b2,
                                                   float* __restrict__ out) {
    const int node = (blockIdx.x * 256 + threadIdx.x) >> 6;
    const int lane = threadIdx.x & 63;
    const int oct = lane >> 3;
    const int fl = lane & 7;
    const float ad = al_d[node];
    const int start = offsets[node];
    const int end = offsets[node + 1];

    float s = 0.f;
    float acc[8] = {};

    {
        const int idx = start + oct;
        const int src0 = csr_src[idx];
        float sc = (idx < end) ? al_s[src0] : -__builtin_inff();
        short8 v = *(const short8*)&h2[(size_t)src0 * NCLSP + fl * 8];

        for (int i = start; i < end; i += 8) {
            const int j = i + 8 + oct;
            const int nsrc = csr_src[j];
            const float nsc = (j < end) ? al_s[nsrc] : -__builtin_inff();
            const short8 nv = *(const short8*)&h2[(size_t)nsrc * NCLSP + fl * 8];
            float e_ = sc + ad;
            e_ = e_ > 0.f ? e_ : NEG_SLOPE * e_;
            const float p = __expf(e_);
            s += p;
            #pragma unroll
            for (int k = 0; k < 8; ++k)
                acc[k] = fmaf(p, bf2f((unsigned short)v[k]), acc[k]);
            sc = nsc; v = nv;
        }
    }
    s += __shfl_xor(s, 8);
    s += __shfl_xor(s, 16);
    s += __shfl_xor(s, 32);
    #pragma unroll
    for (int k = 0; k < 8; ++k) {
        acc[k] += __shfl_xor(acc[k], 8);
        acc[k] += __shfl_xor(acc[k], 16);
        acc[k] += __shfl_xor(acc[k], 32);
    }

    if (oct == 0) {
        const float inv = 1.f / (s + 1e-16f);
        float o[8];
        float mx = -1e30f;
        #pragma unroll
        for (int k = 0; k < 8; ++k) {
            const int c = fl * 8 + k;
            const float bc = (c < NCLS) ? b2[c] : 0.f;
            o[k] = acc[k] * inv + bc;
            if (c < NCLS) mx = fmaxf(mx, o[k]);
        }
        #pragma unroll
        for (int off = 1; off < 8; off <<= 1) mx = fmaxf(mx, __shfl_xor(mx, off));
        float ex = 0.f;
        #pragma unroll
        for (int k = 0; k < 8; ++k) {
            const int c = fl * 8 + k;
            if (c < NCLS) ex += __expf(o[k] - mx);
        }
        #pragma unroll
        for (int off = 1; off < 8; off <<= 1) ex += __shfl_xor(ex, off);
        const float lse = mx + logf(ex);
        if (fl < 5) {
            float4 r0, r1;
            r0.x = o[0] - lse; r0.y = o[1] - lse; r0.z = o[2] - lse; r0.w = o[3] - lse;
            r1.x = o[4] - lse; r1.y = o[5] - lse; r1.z = o[6] - lse; r1.w = o[7] - lse;
            *(float4*)&out[(size_t)node * NCLS + fl * 8] = r0;
            *(float4*)&out[(size_t)node * NCLS + fl * 8 + 4] = r1;
        }
    }
}

// ---------------- launch: 5 dispatches (was 10) ------------------------------
extern "C" void kernel_launch(void* const* d_in, const int* in_sizes, int n_in,
                              void* d_out, int out_size, void* d_ws, size_t ws_size,
                              hipStream_t stream) {
    const float* x      = (const float*)d_in[0];
    const int*   ei     = (const int*)d_in[1];
    const float* W1     = (const float*)d_in[2];
    const float* a_src1 = (const float*)d_in[3];
    const float* a_dst1 = (const float*)d_in[4];
    const float* b1     = (const float*)d_in[5];
    const float* W2     = (const float*)d_in[6];
    const float* a_src2 = (const float*)d_in[7];
    const float* a_dst2 = (const float*)d_in[8];
    const float* b2     = (const float*)d_in[9];
    float* out = (float*)d_out;
    const int E = in_sizes[1] / 2;

    char* ws = (char*)d_ws;
    size_t off = 0;
    auto alloc = [&](size_t bytes) -> char* {
        char* p = ws + off;
        off += (bytes + 255) & ~(size_t)255;
        return p;
    };
    unsigned short* W1t   = (unsigned short*)alloc((size_t)FIN * HD * 2);
    unsigned short* W2t   = (unsigned short*)alloc((size_t)NCLSP * HD * 2);
    unsigned short* h1    = (unsigned short*)alloc((size_t)NNODES * HD * 2);
    unsigned short* h_act = (unsigned short*)alloc((size_t)NNODES * HD * 2);
    unsigned short* h2    = (unsigned short*)alloc((size_t)NNODES * NCLSP * 2);
    float* al_s1  = (float*)alloc((size_t)NNODES * HEADS * 4);
    float* al_d1  = (float*)alloc((size_t)NNODES * HEADS * 4);
    float* al_s2  = (float*)alloc((size_t)NNODES * 4);
    float* al_d2  = (float*)alloc((size_t)NNODES * 4);
    int*   deg    = (int*)alloc((size_t)NNODES * 4);
    int*   cursor = (int*)alloc((size_t)NNODES * 4);
    int*   psum   = (int*)alloc((size_t)NNODES * 4);
    int*   bsum   = (int*)alloc((size_t)SBLK * 4);
    int*   offs   = (int*)alloc((size_t)(NNODES + 1) * 4);
    int*   csrsrc = (int*)alloc((size_t)E * 4 + 256);  // +64 safe pad entries

    // cooperative CSR build (zero + deg + W transposes + scans + scatter)
    {
        void* args[] = {(void*)&ei, (void*)&E, (void*)&W1, (void*)&W1t,
                        (void*)&W2, (void*)&W2t, (void*)&deg, (void*)&cursor,
                        (void*)&psum, (void*)&bsum, (void*)&offs, (void*)&csrsrc};
        hipLaunchCooperativeKernel((void*)csr_kernel, dim3(960), dim3(256),
                                   args, 0, stream);
    }

    gemm1_kernel<<<G1BLK, 256, 0, stream>>>(x, W1t, a_src1, a_dst1, h1, al_s1, al_d1);
    agg1_kernel<<<NNODES / 4, 256, 0, stream>>>(h1, al_s1, al_d1, offs, csrsrc, b1, h_act);
    gemm2_kernel<<<(NNODES + G2M - 1) / G2M, 256, 0, stream>>>(h_act, W2t, a_src2, a_dst2, h2, al_s2, al_d2);
    agg2_kernel<<<NNODES / 4, 256, 0, stream>>>(h2, al_s2, al_d2, offs, csrsrc, b2, out);
}

// Round 9
// 376.008 us; speedup vs baseline: 2.1224x; 2.1224x over previous
//
#include <hip/hip_runtime.h>
#include <math.h>

#define NNODES 50000
#define FIN 512
#define HID 64
#define HEADS 4
#define HD (HEADS * HID)   // 256
#define NCLS 40
#define NCLSP 64           // padded to 4x16 MFMA n-tiles; pow2 for 8-lane-per-edge agg2
#define NEG_SLOPE 0.2f
#define SBLK 256
#define NSCAN ((NNODES + SBLK - 1) / SBLK)   // 196

#define W1TBLK (FIN * HD / 256)              // 512
#define W2TBLK NCLSP                         // 64

typedef __attribute__((ext_vector_type(8))) short short8;
typedef __attribute__((ext_vector_type(4))) float f32x4;

static __device__ inline unsigned short f2bf(float f) {
    unsigned int u = __builtin_bit_cast(unsigned int, f);
    unsigned int r = (u + 0x7FFFu + ((u >> 16) & 1u)) >> 16;
    return (unsigned short)r;
}
static __device__ inline float bf2f(unsigned short b) {
    return __builtin_bit_cast(float, (unsigned int)b << 16);
}
static __device__ inline void gload_lds16(const void* g, void* l) {
    __builtin_amdgcn_global_load_lds(
        (const __attribute__((address_space(1))) unsigned int*)g,
        (__attribute__((address_space(3))) unsigned int*)l, 16, 0, 0);
}

// ---------------- preprocess: deg count (+edge rank) + csr pad + W1t + W2t ---
// rank[e] = this edge's arrival index among its dst's edges (free byproduct
// of the degree atomic) -> scatter needs no cursor and no second atomic.
__global__ __launch_bounds__(256) void pre_kernel(const float* __restrict__ W1,
                                                  unsigned short* __restrict__ W1t,
                                                  const float* __restrict__ W2,
                                                  unsigned short* __restrict__ W2t,
                                                  const int* __restrict__ ei, int E, int eb,
                                                  int* __restrict__ deg,
                                                  int* __restrict__ rank,
                                                  int* __restrict__ csr_pad) {
    const int b = blockIdx.x;
    const int tid = threadIdx.x;
    if (b < eb) {
        const int e = b * 256 + tid;
        if (e < E) rank[e] = atomicAdd(&deg[ei[E + e]], 1);
        if (b == 0 && tid < 64) csr_pad[tid] = 0;   // safe pad for clamp-free agg loops
    } else if (b < eb + W1TBLK) {
        // W1[512,256] fp32 -> W1t[256,512] bf16
        const int idx = (b - eb) * 256 + tid;
        const int k = idx >> 8;
        const int n = idx & 255;
        W1t[n * FIN + k] = f2bf(W1[idx]);
    } else {
        // W2[256,40] fp32 -> W2t[64][256] bf16, rows 40..63 zero
        const int idx = (b - eb - W1TBLK) * 256 + tid;
        const int n = idx >> 8;
        const int k = idx & 255;
        W2t[n * HD + k] = (n < NCLS) ? f2bf(W2[k * NCLS + n]) : (unsigned short)0;
    }
}

// ---------------- GEMM1: BM=64 BN=256 BK=32, all-DMA staging (R6 proven) -----
#define BM 64
#define BN 256
#define BK 32
#define G1BLK ((NNODES + BM - 1) / BM)   // 782

__global__ __launch_bounds__(256) void gemm1_kernel(const float* __restrict__ x,
                                                    const unsigned short* __restrict__ W1t,
                                                    const float* __restrict__ a_src,
                                                    const float* __restrict__ a_dst,
                                                    unsigned short* __restrict__ h1,
                                                    float* __restrict__ al_s,
                                                    float* __restrict__ al_d) {
    __shared__ float As32[2][BM * BK];         // 2 x 8 KB  [row][32 fp32] (swizzled chunks)
    __shared__ unsigned short Bs[2][BN * BK];  // 2 x 16 KB [n][k] bf16
    const int tid = threadIdx.x;
    const int wave = tid >> 6;
    const int lane = tid & 63;
    const int quad = lane >> 4;
    const int col = lane & 15;
    const int m0 = blockIdx.x * BM;
    const int srow = lane >> 2;          // 0..15 within a 16-row group
    const int skk = (lane & 3) * 8;      // 8-elem bf16 (16B) k-chunk
    const int l3 = lane >> 3;            // row within 8-row group
    const int ch = lane & 7;             // stored 16B chunk within 128B row
    const int chs = ch ^ l3;             // swizzled source chunk (row&7 == l3)

    f32x4 acc[4][4] = {};

    auto stageA = [&](int buf, int k0) {
        #pragma unroll
        for (int j = 0; j < 2; ++j) {
            const int row = wave * 16 + j * 8 + l3;
            const size_t rg = (size_t)min(m0 + row, NNODES - 1) * FIN;  // clamped
            gload_lds16(&x[rg + k0 + chs * 4], &As32[buf][row * BK + ch * 4]);
        }
    };
    auto stageB = [&](int buf, int k0) {
        #pragma unroll
        for (int c = 0; c < 4; ++c) {
            const int rr = c * 64 + wave * 16 + srow;
            gload_lds16(&W1t[(size_t)rr * FIN + k0 + skk], &Bs[buf][rr * BK + skk]);
        }
    };
    auto compute = [&](int buf) {
        const int r7 = col & 7;          // (i*16+col)&7 for all i
        short8 af[4], bfv[4];
        #pragma unroll
        for (int i = 0; i < 4; ++i) {
            const int row = i * 16 + col;
            const float4 f0 = *(const float4*)&As32[buf][row * BK + (((2 * quad)     ^ r7) << 2)];
            const float4 f1 = *(const float4*)&As32[buf][row * BK + (((2 * quad + 1) ^ r7) << 2)];
            short8 p;
            p[0] = (short)f2bf(f0.x); p[1] = (short)f2bf(f0.y);
            p[2] = (short)f2bf(f0.z); p[3] = (short)f2bf(f0.w);
            p[4] = (short)f2bf(f1.x); p[5] = (short)f2bf(f1.y);
            p[6] = (short)f2bf(f1.z); p[7] = (short)f2bf(f1.w);
            af[i] = p;
        }
        #pragma unroll
        for (int j = 0; j < 4; ++j)
            bfv[j] = *(const short8*)&Bs[buf][(wave * 64 + j * 16 + col) * BK + quad * 8];
        #pragma unroll
        for (int i = 0; i < 4; ++i)
            #pragma unroll
            for (int j = 0; j < 4; ++j)
                acc[i][j] = __builtin_amdgcn_mfma_f32_16x16x32_bf16(af[i], bfv[j], acc[i][j], 0, 0, 0);
    };

    stageA(0, 0);
    stageB(0, 0);
    __syncthreads();
    int cur = 0;
    for (int k0 = BK; k0 < FIN; k0 += BK) {
        stageA(cur ^ 1, k0);   // async DMAs fly under compute, drain at barrier
        stageB(cur ^ 1, k0);
        compute(cur);
        __syncthreads();
        cur ^= 1;
    }
    compute(cur);

    // epilogue: h1 write + fused per-head attention score dots (head == wave)
    float asv[4], adv[4];
    #pragma unroll
    for (int j = 0; j < 4; ++j) {
        asv[j] = a_src[wave * 64 + j * 16 + col];
        adv[j] = a_dst[wave * 64 + j * 16 + col];
    }
    #pragma unroll
    for (int i = 0; i < 4; ++i) {
        #pragma unroll
        for (int reg = 0; reg < 4; ++reg) {
            const int row = i * 16 + quad * 4 + reg;
            const int gm = m0 + row;
            float ds = 0.f, dd = 0.f;
            #pragma unroll
            for (int j = 0; j < 4; ++j) {
                const float v = acc[i][j][reg];
                ds = fmaf(v, asv[j], ds);
                dd = fmaf(v, adv[j], dd);
                if (gm < NNODES) {
                    const int gc = wave * 64 + j * 16 + col;
                    h1[(size_t)gm * HD + gc] = f2bf(v);
                }
            }
            #pragma unroll
            for (int off = 1; off < 16; off <<= 1) {
                ds += __shfl_xor(ds, off);
                dd += __shfl_xor(dd, off);
            }
            if (col == 0 && gm < NNODES) {
                al_s[gm * HEADS + wave] = ds;
                al_d[gm * HEADS + wave] = dd;
            }
        }
    }
}

// ---------------- CSR build: scans ------------------------------------------
__global__ __launch_bounds__(SBLK) void scan1_kernel(const int* __restrict__ deg,
                                                     int* __restrict__ psum,
                                                     int* __restrict__ bsum) {
    __shared__ int ws[4];
    const int t = threadIdx.x;
    const int idx = blockIdx.x * SBLK + t;
    const int lane = t & 63;
    const int w = t >> 6;
    int sv = (idx < NNODES) ? deg[idx] : 0;
    #pragma unroll
    for (int off = 1; off < 64; off <<= 1) {
        const int n = __shfl_up(sv, off);
        if (lane >= off) sv += n;
    }
    if (lane == 63) ws[w] = sv;
    __syncthreads();
    int add = 0;
    for (int i = 0; i < w; ++i) add += ws[i];
    sv += add;
    if (idx < NNODES) psum[idx] = sv;
    if (t == SBLK - 1) bsum[blockIdx.x] = sv;
}

__global__ __launch_bounds__(SBLK) void scan23_kernel(const int* __restrict__ deg,
                                                      const int* __restrict__ psum,
                                                      const int* __restrict__ bsum,
                                                      int* __restrict__ offsets) {
    __shared__ int ws[4];
    __shared__ int sc[NSCAN];
    const int t = threadIdx.x;
    const int lane = t & 63;
    const int w = t >> 6;
    int sv = (t < NSCAN) ? bsum[t] : 0;
    #pragma unroll
    for (int off = 1; off < 64; off <<= 1) {
        const int n = __shfl_up(sv, off);
        if (lane >= off) sv += n;
    }
    if (lane == 63) ws[w] = sv;
    __syncthreads();
    int add = 0;
    for (int i = 0; i < w; ++i) add += ws[i];
    sv += add;
    if (t < NSCAN) sc[t] = sv;
    __syncthreads();
    const int idx = blockIdx.x * SBLK + t;
    const int boff = (blockIdx.x > 0) ? sc[blockIdx.x - 1] : 0;
    if (idx < NNODES) offsets[idx] = psum[idx] - deg[idx] + boff;
    if (blockIdx.x == 0 && t == 0) offsets[NNODES] = sc[NSCAN - 1];
}

// scatter without atomics: pos = offs[dst] + rank[e] (rank from deg pass)
__global__ void scatter_kernel(const int* __restrict__ ei, int E,
                               const int* __restrict__ offsets,
                               const int* __restrict__ rank,
                               int* __restrict__ csr_src) {
    const int e = blockIdx.x * 256 + threadIdx.x;
    if (e < E) {
        const int dst = ei[E + e];
        const int src = ei[e];
        csr_src[offsets[dst] + rank[e]] = src;
    }
}

// ---------------- layer-1 aggregation: quarter-wave-per-edge, 4 streams ------
// (R6 proven form: 75.4 us)
__global__ __launch_bounds__(256) void agg1_kernel(const unsigned short* __restrict__ h1,
                                                   const float* __restrict__ al_s,
                                                   const float* __restrict__ al_d,
                                                   const int* __restrict__ offsets,
                                                   const int* __restrict__ csr_src,
                                                   const float* __restrict__ b1,
                                                   unsigned short* __restrict__ h_act) {
    const int node = (blockIdx.x * 256 + threadIdx.x) >> 6;
    const int lane = threadIdx.x & 63;
    const int q = lane >> 4;         // edge stream 0..3
    const int fl = lane & 15;        // feature group: feats fl*16 .. fl*16+15
    const int h = fl >> 2;           // head for this feature group
    const float ad = al_d[node * HEADS + h];
    const int start = offsets[node];
    const int end = offsets[node + 1];

    float s = 0.f;
    float acc[16] = {};

    {
        const int idx = start + q;
        const int src0 = csr_src[idx];
        float sc = (idx < end) ? al_s[src0 * HEADS + h] : -__builtin_inff();
        uint4 v0 = *(const uint4*)&h1[(size_t)src0 * HD + fl * 16];
        uint4 v1 = *(const uint4*)&h1[(size_t)src0 * HD + fl * 16 + 8];

        for (int i = start; i < end; i += 4) {
            const int j = i + 4 + q;
            const int nsrc = csr_src[j];
            const float nsc = (j < end) ? al_s[nsrc * HEADS + h] : -__builtin_inff();
            const uint4 nv0 = *(const uint4*)&h1[(size_t)nsrc * HD + fl * 16];
            const uint4 nv1 = *(const uint4*)&h1[(size_t)nsrc * HD + fl * 16 + 8];
            float e_ = sc + ad;
            e_ = e_ > 0.f ? e_ : NEG_SLOPE * e_;
            const float p = __expf(e_);
            s += p;
            const unsigned int w[8] = {v0.x, v0.y, v0.z, v0.w, v1.x, v1.y, v1.z, v1.w};
            #pragma unroll
            for (int d = 0; d < 8; ++d) {
                const float lo = __builtin_bit_cast(float, w[d] << 16);
                const float hi = __builtin_bit_cast(float, w[d] & 0xFFFF0000u);
                acc[2 * d]     = fmaf(p, lo, acc[2 * d]);
                acc[2 * d + 1] = fmaf(p, hi, acc[2 * d + 1]);
            }
            sc = nsc; v0 = nv0; v1 = nv1;
        }
    }
    s += __shfl_xor(s, 16);
    s += __shfl_xor(s, 32);
    #pragma unroll
    for (int k = 0; k < 16; ++k) {
        acc[k] += __shfl_xor(acc[k], 16);
        acc[k] += __shfl_xor(acc[k], 32);
    }

    if (q == 0) {
        const float inv = 1.f / (s + 1e-16f);
        float bb[16];
        *(float4*)&bb[0]  = *(const float4*)&b1[fl * 16];
        *(float4*)&bb[4]  = *(const float4*)&b1[fl * 16 + 4];
        *(float4*)&bb[8]  = *(const float4*)&b1[fl * 16 + 8];
        *(float4*)&bb[12] = *(const float4*)&b1[fl * 16 + 12];
        short8 ob0, ob1;
        #pragma unroll
        for (int k = 0; k < 8; ++k) {
            const float o0 = acc[k] * inv + bb[k];
            const float o1 = acc[8 + k] * inv + bb[8 + k];
            const float e0 = o0 > 0.f ? o0 : expm1f(o0);
            const float e1 = o1 > 0.f ? o1 : expm1f(o1);
            ob0[k] = (short)f2bf(e0);
            ob1[k] = (short)f2bf(e1);
        }
        *(short8*)&h_act[(size_t)node * HD + fl * 16] = ob0;
        *(short8*)&h_act[(size_t)node * HD + fl * 16 + 8] = ob1;
    }
}

// ---------------- GEMM2 via MFMA: h2[N,64] = h_act[N,256] @ W2pad + dots -----
#define G2M 64
#define BSTRIDE 264

__global__ __launch_bounds__(256) void gemm2_kernel(const unsigned short* __restrict__ h_act,
                                                    const unsigned short* __restrict__ W2t,
                                                    const float* __restrict__ a_s2,
                                                    const float* __restrict__ a_d2,
                                                    unsigned short* __restrict__ h2,
                                                    float* __restrict__ al_s,
                                                    float* __restrict__ al_d) {
    __shared__ unsigned short Bt[NCLSP][BSTRIDE];
    const int tid = threadIdx.x;
    const int wave = tid >> 6;
    const int lane = tid & 63;
    const int quad = lane >> 4;
    const int col = lane & 15;
    const int m0 = blockIdx.x * G2M;

    #pragma unroll
    for (int it = 0; it < 8; ++it) {
        const int ch = it * 256 + tid;
        const int n = ch >> 5;
        const int c8 = (ch & 31) * 8;
        *(uint4*)&Bt[n][c8] = *(const uint4*)&W2t[(size_t)n * HD + c8];
    }

    const int rowm = m0 + wave * 16 + col;
    const int arow = min(rowm, NNODES - 1);
    short8 af[8];
    #pragma unroll
    for (int ks = 0; ks < 8; ++ks)
        af[ks] = *(const short8*)&h_act[(size_t)arow * HD + ks * 32 + quad * 8];

    __syncthreads();

    f32x4 acc[4] = {};
    #pragma unroll
    for (int j = 0; j < 4; ++j) {
        #pragma unroll
        for (int ks = 0; ks < 8; ++ks) {
            const short8 bfr = *(const short8*)&Bt[j * 16 + col][ks * 32 + quad * 8];
            acc[j] = __builtin_amdgcn_mfma_f32_16x16x32_bf16(af[ks], bfr, acc[j], 0, 0, 0);
        }
    }

    float ps[4] = {0.f, 0.f, 0.f, 0.f};
    float pd[4] = {0.f, 0.f, 0.f, 0.f};
    #pragma unroll
    for (int j = 0; j < 4; ++j) {
        const int c = j * 16 + col;
        const bool cv = c < NCLS;
        const float asc = cv ? a_s2[c] : 0.f;
        const float adc = cv ? a_d2[c] : 0.f;
        #pragma unroll
        for (int reg = 0; reg < 4; ++reg) {
            const float v = acc[j][reg];
            ps[reg] += v * asc;
            pd[reg] += v * adc;
            const int node = m0 + wave * 16 + quad * 4 + reg;
            if (node < NNODES)
                h2[(size_t)node * NCLSP + c] = f2bf(v);
        }
    }
    #pragma unroll
    for (int reg = 0; reg < 4; ++reg) {
        #pragma unroll
        for (int off = 1; off < 16; off <<= 1) {
            ps[reg] += __shfl_xor(ps[reg], off);
            pd[reg] += __shfl_xor(pd[reg], off);
        }
    }
    if (col == 0) {
        #pragma unroll
        for (int reg = 0; reg < 4; ++reg) {
            const int node = m0 + wave * 16 + quad * 4 + reg;
            if (node < NNODES) {
                al_s[node] = ps[reg];
                al_d[node] = pd[reg];
            }
        }
    }
}

// ---------------- layer-2 aggregation: octet-per-edge, 8 streams -------------
__global__ __launch_bounds__(256) void agg2_kernel(const unsigned short* __restrict__ h2,
                                                   const float* __restrict__ al_s,
                                                   const float* __restrict__ al_d,
                                                   const int* __restrict__ offsets,
                                                   const int* __restrict__ csr_src,
                                                   const float* __restrict__ b2,
                                                   float* __restrict__ out) {
    const int node = (blockIdx.x * 256 + threadIdx.x) >> 6;
    const int lane = threadIdx.x & 63;
    const int oct = lane >> 3;
    const int fl = lane & 7;
    const float ad = al_d[node];
    const int start = offsets[node];
    const int end = offsets[node + 1];

    float s = 0.f;
    float acc[8] = {};

    {
        const int idx = start + oct;
        const int src0 = csr_src[idx];
        float sc = (idx < end) ? al_s[src0] : -__builtin_inff();
        short8 v = *(const short8*)&h2[(size_t)src0 * NCLSP + fl * 8];

        for (int i = start; i < end; i += 8) {
            const int j = i + 8 + oct;
            const int nsrc = csr_src[j];
            const float nsc = (j < end) ? al_s[nsrc] : -__builtin_inff();
            const short8 nv = *(const short8*)&h2[(size_t)nsrc * NCLSP + fl * 8];
            float e_ = sc + ad;
            e_ = e_ > 0.f ? e_ : NEG_SLOPE * e_;
            const float p = __expf(e_);
            s += p;
            #pragma unroll
            for (int k = 0; k < 8; ++k)
                acc[k] = fmaf(p, bf2f((unsigned short)v[k]), acc[k]);
            sc = nsc; v = nv;
        }
    }
    s += __shfl_xor(s, 8);
    s += __shfl_xor(s, 16);
    s += __shfl_xor(s, 32);
    #pragma unroll
    for (int k = 0; k < 8; ++k) {
        acc[k] += __shfl_xor(acc[k], 8);
        acc[k] += __shfl_xor(acc[k], 16);
        acc[k] += __shfl_xor(acc[k], 32);
    }

    if (oct == 0) {
        const float inv = 1.f / (s + 1e-16f);
        float o[8];
        float mx = -1e30f;
        #pragma unroll
        for (int k = 0; k < 8; ++k) {
            const int c = fl * 8 + k;
            const float bc = (c < NCLS) ? b2[c] : 0.f;
            o[k] = acc[k] * inv + bc;
            if (c < NCLS) mx = fmaxf(mx, o[k]);
        }
        #pragma unroll
        for (int off = 1; off < 8; off <<= 1) mx = fmaxf(mx, __shfl_xor(mx, off));
        float ex = 0.f;
        #pragma unroll
        for (int k = 0; k < 8; ++k) {
            const int c = fl * 8 + k;
            if (c < NCLS) ex += __expf(o[k] - mx);
        }
        #pragma unroll
        for (int off = 1; off < 8; off <<= 1) ex += __shfl_xor(ex, off);
        const float lse = mx + logf(ex);
        if (fl < 5) {
            float4 r0, r1;
            r0.x = o[0] - lse; r0.y = o[1] - lse; r0.z = o[2] - lse; r0.w = o[3] - lse;
            r1.x = o[4] - lse; r1.y = o[5] - lse; r1.z = o[6] - lse; r1.w = o[7] - lse;
            *(float4*)&out[(size_t)node * NCLS + fl * 8] = r0;
            *(float4*)&out[(size_t)node * NCLS + fl * 8 + 4] = r1;
        }
    }
}

// ---------------- launch: 9 dispatches ---------------------------------------
extern "C" void kernel_launch(void* const* d_in, const int* in_sizes, int n_in,
                              void* d_out, int out_size, void* d_ws, size_t ws_size,
                              hipStream_t stream) {
    const float* x      = (const float*)d_in[0];
    const int*   ei     = (const int*)d_in[1];
    const float* W1     = (const float*)d_in[2];
    const float* a_src1 = (const float*)d_in[3];
    const float* a_dst1 = (const float*)d_in[4];
    const float* b1     = (const float*)d_in[5];
    const float* W2     = (const float*)d_in[6];
    const float* a_src2 = (const float*)d_in[7];
    const float* a_dst2 = (const float*)d_in[8];
    const float* b2     = (const float*)d_in[9];
    float* out = (float*)d_out;
    const int E = in_sizes[1] / 2;

    char* ws = (char*)d_ws;
    size_t off = 0;
    auto alloc = [&](size_t bytes) -> char* {
        char* p = ws + off;
        off += (bytes + 255) & ~(size_t)255;
        return p;
    };
    unsigned short* W1t   = (unsigned short*)alloc((size_t)FIN * HD * 2);
    unsigned short* W2t   = (unsigned short*)alloc((size_t)NCLSP * HD * 2);
    unsigned short* h1    = (unsigned short*)alloc((size_t)NNODES * HD * 2);
    unsigned short* h_act = (unsigned short*)alloc((size_t)NNODES * HD * 2);
    unsigned short* h2    = (unsigned short*)alloc((size_t)NNODES * NCLSP * 2);
    float* al_s1  = (float*)alloc((size_t)NNODES * HEADS * 4);
    float* al_d1  = (float*)alloc((size_t)NNODES * HEADS * 4);
    float* al_s2  = (float*)alloc((size_t)NNODES * 4);
    float* al_d2  = (float*)alloc((size_t)NNODES * 4);
    int*   deg    = (int*)alloc((size_t)NNODES * 4);
    int*   rank   = (int*)alloc((size_t)E * 4);
    int*   psum   = (int*)alloc((size_t)NNODES * 4);
    int*   bsum   = (int*)alloc((size_t)SBLK * 4);
    int*   offs   = (int*)alloc((size_t)(NNODES + 1) * 4);
    int*   csrsrc = (int*)alloc((size_t)E * 4 + 256);  // +64 safe pad entries

    hipMemsetAsync(deg, 0, (size_t)NNODES * 4, stream);

    const int eb = (E + 255) / 256;
    pre_kernel<<<eb + W1TBLK + W2TBLK, 256, 0, stream>>>(W1, W1t, W2, W2t, ei, E, eb, deg, rank, csrsrc + E);
    scan1_kernel<<<NSCAN, SBLK, 0, stream>>>(deg, psum, bsum);
    scan23_kernel<<<NSCAN, SBLK, 0, stream>>>(deg, psum, bsum, offs);
    scatter_kernel<<<eb, 256, 0, stream>>>(ei, E, offs, rank, csrsrc);

    gemm1_kernel<<<G1BLK, 256, 0, stream>>>(x, W1t, a_src1, a_dst1, h1, al_s1, al_d1);
    agg1_kernel<<<NNODES / 4, 256, 0, stream>>>(h1, al_s1, al_d1, offs, csrsrc, b1, h_act);
    gemm2_kernel<<<(NNODES + G2M - 1) / G2M, 256, 0, stream>>>(h_act, W2t, a_src2, a_dst2, h2, al_s2, al_d2);
    agg2_kernel<<<NNODES / 4, 256, 0, stream>>>(h2, al_s2, al_d2, offs, csrsrc, b2, out);
}

// Round 10
// 366.337 us; speedup vs baseline: 2.1784x; 1.0264x over previous
//
#include <hip/hip_runtime.h>
#include <math.h>

#define NNODES 50000
#define FIN 512
#define HID 64
#define HEADS 4
#define HD (HEADS * HID)   // 256
#define NCLS 40
#define NCLSP 64           // padded to 4x16 MFMA n-tiles; pow2 for 8-lane-per-edge agg2
#define NEG_SLOPE 0.2f
#define SBLK 256
#define NSCAN ((NNODES + SBLK - 1) / SBLK)   // 196

#define W1TBLK (FIN * HD / 256)              // 512
#define W2TBLK NCLSP                         // 64

typedef __attribute__((ext_vector_type(8))) short short8;
typedef __attribute__((ext_vector_type(4))) float f32x4;

static __device__ inline unsigned short f2bf(float f) {
    unsigned int u = __builtin_bit_cast(unsigned int, f);
    unsigned int r = (u + 0x7FFFu + ((u >> 16) & 1u)) >> 16;
    return (unsigned short)r;
}
static __device__ inline float bf2f(unsigned short b) {
    return __builtin_bit_cast(float, (unsigned int)b << 16);
}
static __device__ inline void gload_lds16(const void* g, void* l) {
    __builtin_amdgcn_global_load_lds(
        (const __attribute__((address_space(1))) unsigned int*)g,
        (__attribute__((address_space(3))) unsigned int*)l, 16, 0, 0);
}

// ---------------- preprocess: deg count (+edge rank) + csr pad + W1t + W2t ---
// rank[e] = this edge's arrival index among its dst's edges (free byproduct
// of the degree atomic) -> scatter needs no cursor and no second atomic.
__global__ __launch_bounds__(256) void pre_kernel(const float* __restrict__ W1,
                                                  unsigned short* __restrict__ W1t,
                                                  const float* __restrict__ W2,
                                                  unsigned short* __restrict__ W2t,
                                                  const int* __restrict__ ei, int E, int eb,
                                                  int* __restrict__ deg,
                                                  int* __restrict__ rank,
                                                  int* __restrict__ csr_pad) {
    const int b = blockIdx.x;
    const int tid = threadIdx.x;
    if (b < eb) {
        const int e = b * 256 + tid;
        if (e < E) rank[e] = atomicAdd(&deg[ei[E + e]], 1);
        if (b == 0 && tid < 64) csr_pad[tid] = 0;   // safe pad for clamp-free agg loops
    } else if (b < eb + W1TBLK) {
        // W1[512,256] fp32 -> W1t[256,512] bf16
        const int idx = (b - eb) * 256 + tid;
        const int k = idx >> 8;
        const int n = idx & 255;
        W1t[n * FIN + k] = f2bf(W1[idx]);
    } else {
        // W2[256,40] fp32 -> W2t[64][256] bf16, rows 40..63 zero
        const int idx = (b - eb - W1TBLK) * 256 + tid;
        const int n = idx >> 8;
        const int k = idx & 255;
        W2t[n * HD + k] = (n < NCLS) ? f2bf(W2[k * NCLS + n]) : (unsigned short)0;
    }
}

// ---------------- GEMM1: BM=128 BN=256 BK=32, 8 waves, all-DMA staging -------
// BM 64->128: 2x MFMA per block at same per-wave LDS cost, half the barriers
// per output, half the per-output B-stage traffic. Wave (wr,wc)=(w>>2,w&3);
// wc's 64-col slice == head wc, so the fused score-dot epilogue is unchanged.
// A staged as fp32 via global_load_lds with chunk-XOR swizzle (rule #21:
// linear dest + inverse-swizzled source + swizzled read). 64 KB LDS.
#define BM 128
#define BN 256
#define BK 32
#define G1BLK ((NNODES + BM - 1) / BM)   // 391

__global__ __launch_bounds__(512) void gemm1_kernel(const float* __restrict__ x,
                                                    const unsigned short* __restrict__ W1t,
                                                    const float* __restrict__ a_src,
                                                    const float* __restrict__ a_dst,
                                                    unsigned short* __restrict__ h1,
                                                    float* __restrict__ al_s,
                                                    float* __restrict__ al_d) {
    __shared__ float As32[2][BM * BK];         // 2 x 16 KB [row][32 fp32] (swizzled chunks)
    __shared__ unsigned short Bs[2][BN * BK];  // 2 x 16 KB [n][k] bf16
    const int tid = threadIdx.x;
    const int wave = tid >> 6;           // 0..7
    const int wr = wave >> 2;            // output row half (0/1)
    const int wc = wave & 3;             // output col slice == head
    const int lane = tid & 63;
    const int quad = lane >> 4;
    const int col = lane & 15;
    const int m0 = blockIdx.x * BM;
    const int srow = lane >> 2;          // 0..15 within a 16-row group
    const int skk = (lane & 3) * 8;      // 8-elem bf16 (16B) k-chunk
    const int l3 = lane >> 3;            // row within 8-row group
    const int ch = lane & 7;             // stored 16B chunk within 128B row
    const int chs = ch ^ l3;             // swizzled source chunk (row&7 == l3)

    f32x4 acc[4][4] = {};

    auto stageA = [&](int buf, int k0) {
        #pragma unroll
        for (int j = 0; j < 2; ++j) {
            const int row = wave * 16 + j * 8 + l3;              // 0..127
            const size_t rg = (size_t)min(m0 + row, NNODES - 1) * FIN;  // clamped
            gload_lds16(&x[rg + k0 + chs * 4], &As32[buf][row * BK + ch * 4]);
        }
    };
    auto stageB = [&](int buf, int k0) {
        #pragma unroll
        for (int c = 0; c < 2; ++c) {
            const int rr = c * 128 + wave * 16 + srow;           // 0..255
            gload_lds16(&W1t[(size_t)rr * FIN + k0 + skk], &Bs[buf][rr * BK + skk]);
        }
    };
    auto compute = [&](int buf) {
        const int r7 = col & 7;          // (wr*64 + i*16 + col)&7 for all i
        short8 af[4], bfv[4];
        #pragma unroll
        for (int i = 0; i < 4; ++i) {
            const int row = wr * 64 + i * 16 + col;
            const float4 f0 = *(const float4*)&As32[buf][row * BK + (((2 * quad)     ^ r7) << 2)];
            const float4 f1 = *(const float4*)&As32[buf][row * BK + (((2 * quad + 1) ^ r7) << 2)];
            short8 p;
            p[0] = (short)f2bf(f0.x); p[1] = (short)f2bf(f0.y);
            p[2] = (short)f2bf(f0.z); p[3] = (short)f2bf(f0.w);
            p[4] = (short)f2bf(f1.x); p[5] = (short)f2bf(f1.y);
            p[6] = (short)f2bf(f1.z); p[7] = (short)f2bf(f1.w);
            af[i] = p;
        }
        #pragma unroll
        for (int j = 0; j < 4; ++j)
            bfv[j] = *(const short8*)&Bs[buf][(wc * 64 + j * 16 + col) * BK + quad * 8];
        #pragma unroll
        for (int i = 0; i < 4; ++i)
            #pragma unroll
            for (int j = 0; j < 4; ++j)
                acc[i][j] = __builtin_amdgcn_mfma_f32_16x16x32_bf16(af[i], bfv[j], acc[i][j], 0, 0, 0);
    };

    stageA(0, 0);
    stageB(0, 0);
    __syncthreads();
    int cur = 0;
    for (int k0 = BK; k0 < FIN; k0 += BK) {
        stageA(cur ^ 1, k0);   // async DMAs fly under compute, drain at barrier
        stageB(cur ^ 1, k0);
        compute(cur);
        __syncthreads();
        cur ^= 1;
    }
    compute(cur);

    // epilogue: h1 write + fused per-head attention score dots (head == wc)
    float asv[4], adv[4];
    #pragma unroll
    for (int j = 0; j < 4; ++j) {
        asv[j] = a_src[wc * 64 + j * 16 + col];
        adv[j] = a_dst[wc * 64 + j * 16 + col];
    }
    #pragma unroll
    for (int i = 0; i < 4; ++i) {
        #pragma unroll
        for (int reg = 0; reg < 4; ++reg) {
            const int row = wr * 64 + i * 16 + quad * 4 + reg;
            const int gm = m0 + row;
            float ds = 0.f, dd = 0.f;
            #pragma unroll
            for (int j = 0; j < 4; ++j) {
                const float v = acc[i][j][reg];
                ds = fmaf(v, asv[j], ds);
                dd = fmaf(v, adv[j], dd);
                if (gm < NNODES) {
                    const int gc = wc * 64 + j * 16 + col;
                    h1[(size_t)gm * HD + gc] = f2bf(v);
                }
            }
            #pragma unroll
            for (int off = 1; off < 16; off <<= 1) {
                ds += __shfl_xor(ds, off);
                dd += __shfl_xor(dd, off);
            }
            if (col == 0 && gm < NNODES) {
                al_s[gm * HEADS + wc] = ds;
                al_d[gm * HEADS + wc] = dd;
            }
        }
    }
}

// ---------------- CSR build: scans ------------------------------------------
__global__ __launch_bounds__(SBLK) void scan1_kernel(const int* __restrict__ deg,
                                                     int* __restrict__ psum,
                                                     int* __restrict__ bsum) {
    __shared__ int ws[4];
    const int t = threadIdx.x;
    const int idx = blockIdx.x * SBLK + t;
    const int lane = t & 63;
    const int w = t >> 6;
    int sv = (idx < NNODES) ? deg[idx] : 0;
    #pragma unroll
    for (int off = 1; off < 64; off <<= 1) {
        const int n = __shfl_up(sv, off);
        if (lane >= off) sv += n;
    }
    if (lane == 63) ws[w] = sv;
    __syncthreads();
    int add = 0;
    for (int i = 0; i < w; ++i) add += ws[i];
    sv += add;
    if (idx < NNODES) psum[idx] = sv;
    if (t == SBLK - 1) bsum[blockIdx.x] = sv;
}

__global__ __launch_bounds__(SBLK) void scan23_kernel(const int* __restrict__ deg,
                                                      const int* __restrict__ psum,
                                                      const int* __restrict__ bsum,
                                                      int* __restrict__ offsets) {
    __shared__ int ws[4];
    __shared__ int sc[NSCAN];
    const int t = threadIdx.x;
    const int lane = t & 63;
    const int w = t >> 6;
    int sv = (t < NSCAN) ? bsum[t] : 0;
    #pragma unroll
    for (int off = 1; off < 64; off <<= 1) {
        const int n = __shfl_up(sv, off);
        if (lane >= off) sv += n;
    }
    if (lane == 63) ws[w] = sv;
    __syncthreads();
    int add = 0;
    for (int i = 0; i < w; ++i) add += ws[i];
    sv += add;
    if (t < NSCAN) sc[t] = sv;
    __syncthreads();
    const int idx = blockIdx.x * SBLK + t;
    const int boff = (blockIdx.x > 0) ? sc[blockIdx.x - 1] : 0;
    if (idx < NNODES) offsets[idx] = psum[idx] - deg[idx] + boff;
    if (blockIdx.x == 0 && t == 0) offsets[NNODES] = sc[NSCAN - 1];
}

// scatter without atomics: pos = offs[dst] + rank[e] (rank from deg pass)
__global__ void scatter_kernel(const int* __restrict__ ei, int E,
                               const int* __restrict__ offsets,
                               const int* __restrict__ rank,
                               int* __restrict__ csr_src) {
    const int e = blockIdx.x * 256 + threadIdx.x;
    if (e < E) {
        const int dst = ei[E + e];
        const int src = ei[e];
        csr_src[offsets[dst] + rank[e]] = src;
    }
}

// ---------------- layer-1 aggregation: quarter-wave-per-edge, 4 streams ------
// (R6/R9 proven form: 75.4 us — at the random-line L2-fill wall)
__global__ __launch_bounds__(256) void agg1_kernel(const unsigned short* __restrict__ h1,
                                                   const float* __restrict__ al_s,
                                                   const float* __restrict__ al_d,
                                                   const int* __restrict__ offsets,
                                                   const int* __restrict__ csr_src,
                                                   const float* __restrict__ b1,
                                                   unsigned short* __restrict__ h_act) {
    const int node = (blockIdx.x * 256 + threadIdx.x) >> 6;
    const int lane = threadIdx.x & 63;
    const int q = lane >> 4;         // edge stream 0..3
    const int fl = lane & 15;        // feature group: feats fl*16 .. fl*16+15
    const int h = fl >> 2;           // head for this feature group
    const float ad = al_d[node * HEADS + h];
    const int start = offsets[node];
    const int end = offsets[node + 1];

    float s = 0.f;
    float acc[16] = {};

    {
        const int idx = start + q;
        const int src0 = csr_src[idx];
        float sc = (idx < end) ? al_s[src0 * HEADS + h] : -__builtin_inff();
        uint4 v0 = *(const uint4*)&h1[(size_t)src0 * HD + fl * 16];
        uint4 v1 = *(const uint4*)&h1[(size_t)src0 * HD + fl * 16 + 8];

        for (int i = start; i < end; i += 4) {
            const int j = i + 4 + q;
            const int nsrc = csr_src[j];
            const float nsc = (j < end) ? al_s[nsrc * HEADS + h] : -__builtin_inff();
            const uint4 nv0 = *(const uint4*)&h1[(size_t)nsrc * HD + fl * 16];
            const uint4 nv1 = *(const uint4*)&h1[(size_t)nsrc * HD + fl * 16 + 8];
            float e_ = sc + ad;
            e_ = e_ > 0.f ? e_ : NEG_SLOPE * e_;
            const float p = __expf(e_);
            s += p;
            const unsigned int w[8] = {v0.x, v0.y, v0.z, v0.w, v1.x, v1.y, v1.z, v1.w};
            #pragma unroll
            for (int d = 0; d < 8; ++d) {
                const float lo = __builtin_bit_cast(float, w[d] << 16);
                const float hi = __builtin_bit_cast(float, w[d] & 0xFFFF0000u);
                acc[2 * d]     = fmaf(p, lo, acc[2 * d]);
                acc[2 * d + 1] = fmaf(p, hi, acc[2 * d + 1]);
            }
            sc = nsc; v0 = nv0; v1 = nv1;
        }
    }
    s += __shfl_xor(s, 16);
    s += __shfl_xor(s, 32);
    #pragma unroll
    for (int k = 0; k < 16; ++k) {
        acc[k] += __shfl_xor(acc[k], 16);
        acc[k] += __shfl_xor(acc[k], 32);
    }

    if (q == 0) {
        const float inv = 1.f / (s + 1e-16f);
        float bb[16];
        *(float4*)&bb[0]  = *(const float4*)&b1[fl * 16];
        *(float4*)&bb[4]  = *(const float4*)&b1[fl * 16 + 4];
        *(float4*)&bb[8]  = *(const float4*)&b1[fl * 16 + 8];
        *(float4*)&bb[12] = *(const float4*)&b1[fl * 16 + 12];
        short8 ob0, ob1;
        #pragma unroll
        for (int k = 0; k < 8; ++k) {
            const float o0 = acc[k] * inv + bb[k];
            const float o1 = acc[8 + k] * inv + bb[8 + k];
            const float e0 = o0 > 0.f ? o0 : expm1f(o0);
            const float e1 = o1 > 0.f ? o1 : expm1f(o1);
            ob0[k] = (short)f2bf(e0);
            ob1[k] = (short)f2bf(e1);
        }
        *(short8*)&h_act[(size_t)node * HD + fl * 16] = ob0;
        *(short8*)&h_act[(size_t)node * HD + fl * 16 + 8] = ob1;
    }
}

// ---------------- GEMM2 via MFMA: h2[N,64] = h_act[N,256] @ W2pad + dots -----
#define G2M 64
#define BSTRIDE 264

__global__ __launch_bounds__(256) void gemm2_kernel(const unsigned short* __restrict__ h_act,
                                                    const unsigned short* __restrict__ W2t,
                                                    const float* __restrict__ a_s2,
                                                    const float* __restrict__ a_d2,
                                                    unsigned short* __restrict__ h2,
                                                    float* __restrict__ al_s,
                                                    float* __restrict__ al_d) {
    __shared__ unsigned short Bt[NCLSP][BSTRIDE];
    const int tid = threadIdx.x;
    const int wave = tid >> 6;
    const int lane = tid & 63;
    const int quad = lane >> 4;
    const int col = lane & 15;
    const int m0 = blockIdx.x * G2M;

    #pragma unroll
    for (int it = 0; it < 8; ++it) {
        const int ch = it * 256 + tid;
        const int n = ch >> 5;
        const int c8 = (ch & 31) * 8;
        *(uint4*)&Bt[n][c8] = *(const uint4*)&W2t[(size_t)n * HD + c8];
    }

    const int rowm = m0 + wave * 16 + col;
    const int arow = min(rowm, NNODES - 1);
    short8 af[8];
    #pragma unroll
    for (int ks = 0; ks < 8; ++ks)
        af[ks] = *(const short8*)&h_act[(size_t)arow * HD + ks * 32 + quad * 8];

    __syncthreads();

    f32x4 acc[4] = {};
    #pragma unroll
    for (int j = 0; j < 4; ++j) {
        #pragma unroll
        for (int ks = 0; ks < 8; ++ks) {
            const short8 bfr = *(const short8*)&Bt[j * 16 + col][ks * 32 + quad * 8];
            acc[j] = __builtin_amdgcn_mfma_f32_16x16x32_bf16(af[ks], bfr, acc[j], 0, 0, 0);
        }
    }

    float ps[4] = {0.f, 0.f, 0.f, 0.f};
    float pd[4] = {0.f, 0.f, 0.f, 0.f};
    #pragma unroll
    for (int j = 0; j < 4; ++j) {
        const int c = j * 16 + col;
        const bool cv = c < NCLS;
        const float asc = cv ? a_s2[c] : 0.f;
        const float adc = cv ? a_d2[c] : 0.f;
        #pragma unroll
        for (int reg = 0; reg < 4; ++reg) {
            const float v = acc[j][reg];
            ps[reg] += v * asc;
            pd[reg] += v * adc;
            const int node = m0 + wave * 16 + quad * 4 + reg;
            if (node < NNODES)
                h2[(size_t)node * NCLSP + c] = f2bf(v);
        }
    }
    #pragma unroll
    for (int reg = 0; reg < 4; ++reg) {
        #pragma unroll
        for (int off = 1; off < 16; off <<= 1) {
            ps[reg] += __shfl_xor(ps[reg], off);
            pd[reg] += __shfl_xor(pd[reg], off);
        }
    }
    if (col == 0) {
        #pragma unroll
        for (int reg = 0; reg < 4; ++reg) {
            const int node = m0 + wave * 16 + quad * 4 + reg;
            if (node < NNODES) {
                al_s[node] = ps[reg];
                al_d[node] = pd[reg];
            }
        }
    }
}

// ---------------- layer-2 aggregation: octet-per-edge, 8 streams -------------
__global__ __launch_bounds__(256) void agg2_kernel(const unsigned short* __restrict__ h2,
                                                   const float* __restrict__ al_s,
                                                   const float* __restrict__ al_d,
                                                   const int* __restrict__ offsets,
                                                   const int* __restrict__ csr_src,
                                                   const float* __restrict__ b2,
                                                   float* __restrict__ out) {
    const int node = (blockIdx.x * 256 + threadIdx.x) >> 6;
    const int lane = threadIdx.x & 63;
    const int oct = lane >> 3;
    const int fl = lane & 7;
    const float ad = al_d[node];
    const int start = offsets[node];
    const int end = offsets[node + 1];

    float s = 0.f;
    float acc[8] = {};

    {
        const int idx = start + oct;
        const int src0 = csr_src[idx];
        float sc = (idx < end) ? al_s[src0] : -__builtin_inff();
        short8 v = *(const short8*)&h2[(size_t)src0 * NCLSP + fl * 8];

        for (int i = start; i < end; i += 8) {
            const int j = i + 8 + oct;
            const int nsrc = csr_src[j];
            const float nsc = (j < end) ? al_s[nsrc] : -__builtin_inff();
            const short8 nv = *(const short8*)&h2[(size_t)nsrc * NCLSP + fl * 8];
            float e_ = sc + ad;
            e_ = e_ > 0.f ? e_ : NEG_SLOPE * e_;
            const float p = __expf(e_);
            s += p;
            #pragma unroll
            for (int k = 0; k < 8; ++k)
                acc[k] = fmaf(p, bf2f((unsigned short)v[k]), acc[k]);
            sc = nsc; v = nv;
        }
    }
    s += __shfl_xor(s, 8);
    s += __shfl_xor(s, 16);
    s += __shfl_xor(s, 32);
    #pragma unroll
    for (int k = 0; k < 8; ++k) {
        acc[k] += __shfl_xor(acc[k], 8);
        acc[k] += __shfl_xor(acc[k], 16);
        acc[k] += __shfl_xor(acc[k], 32);
    }

    if (oct == 0) {
        const float inv = 1.f / (s + 1e-16f);
        float o[8];
        float mx = -1e30f;
        #pragma unroll
        for (int k = 0; k < 8; ++k) {
            const int c = fl * 8 + k;
            const float bc = (c < NCLS) ? b2[c] : 0.f;
            o[k] = acc[k] * inv + bc;
            if (c < NCLS) mx = fmaxf(mx, o[k]);
        }
        #pragma unroll
        for (int off = 1; off < 8; off <<= 1) mx = fmaxf(mx, __shfl_xor(mx, off));
        float ex = 0.f;
        #pragma unroll
        for (int k = 0; k < 8; ++k) {
            const int c = fl * 8 + k;
            if (c < NCLS) ex += __expf(o[k] - mx);
        }
        #pragma unroll
        for (int off = 1; off < 8; off <<= 1) ex += __shfl_xor(ex, off);
        const float lse = mx + logf(ex);
        if (fl < 5) {
            float4 r0, r1;
            r0.x = o[0] - lse; r0.y = o[1] - lse; r0.z = o[2] - lse; r0.w = o[3] - lse;
            r1.x = o[4] - lse; r1.y = o[5] - lse; r1.z = o[6] - lse; r1.w = o[7] - lse;
            *(float4*)&out[(size_t)node * NCLS + fl * 8] = r0;
            *(float4*)&out[(size_t)node * NCLS + fl * 8 + 4] = r1;
        }
    }
}

// ---------------- launch: 9 dispatches ---------------------------------------
extern "C" void kernel_launch(void* const* d_in, const int* in_sizes, int n_in,
                              void* d_out, int out_size, void* d_ws, size_t ws_size,
                              hipStream_t stream) {
    const float* x      = (const float*)d_in[0];
    const int*   ei     = (const int*)d_in[1];
    const float* W1     = (const float*)d_in[2];
    const float* a_src1 = (const float*)d_in[3];
    const float* a_dst1 = (const float*)d_in[4];
    const float* b1     = (const float*)d_in[5];
    const float* W2     = (const float*)d_in[6];
    const float* a_src2 = (const float*)d_in[7];
    const float* a_dst2 = (const float*)d_in[8];
    const float* b2     = (const float*)d_in[9];
    float* out = (float*)d_out;
    const int E = in_sizes[1] / 2;

    char* ws = (char*)d_ws;
    size_t off = 0;
    auto alloc = [&](size_t bytes) -> char* {
        char* p = ws + off;
        off += (bytes + 255) & ~(size_t)255;
        return p;
    };
    unsigned short* W1t   = (unsigned short*)alloc((size_t)FIN * HD * 2);
    unsigned short* W2t   = (unsigned short*)alloc((size_t)NCLSP * HD * 2);
    unsigned short* h1    = (unsigned short*)alloc((size_t)NNODES * HD * 2);
    unsigned short* h_act = (unsigned short*)alloc((size_t)NNODES * HD * 2);
    unsigned short* h2    = (unsigned short*)alloc((size_t)NNODES * NCLSP * 2);
    float* al_s1  = (float*)alloc((size_t)NNODES * HEADS * 4);
    float* al_d1  = (float*)alloc((size_t)NNODES * HEADS * 4);
    float* al_s2  = (float*)alloc((size_t)NNODES * 4);
    float* al_d2  = (float*)alloc((size_t)NNODES * 4);
    int*   deg    = (int*)alloc((size_t)NNODES * 4);
    int*   rank   = (int*)alloc((size_t)E * 4);
    int*   psum   = (int*)alloc((size_t)NNODES * 4);
    int*   bsum   = (int*)alloc((size_t)SBLK * 4);
    int*   offs   = (int*)alloc((size_t)(NNODES + 1) * 4);
    int*   csrsrc = (int*)alloc((size_t)E * 4 + 256);  // +64 safe pad entries

    hipMemsetAsync(deg, 0, (size_t)NNODES * 4, stream);

    const int eb = (E + 255) / 256;
    pre_kernel<<<eb + W1TBLK + W2TBLK, 256, 0, stream>>>(W1, W1t, W2, W2t, ei, E, eb, deg, rank, csrsrc + E);
    scan1_kernel<<<NSCAN, SBLK, 0, stream>>>(deg, psum, bsum);
    scan23_kernel<<<NSCAN, SBLK, 0, stream>>>(deg, psum, bsum, offs);
    scatter_kernel<<<eb, 256, 0, stream>>>(ei, E, offs, rank, csrsrc);

    gemm1_kernel<<<G1BLK, 512, 0, stream>>>(x, W1t, a_src1, a_dst1, h1, al_s1, al_d1);
    agg1_kernel<<<NNODES / 4, 256, 0, stream>>>(h1, al_s1, al_d1, offs, csrsrc, b1, h_act);
    gemm2_kernel<<<(NNODES + G2M - 1) / G2M, 256, 0, stream>>>(h_act, W2t, a_src2, a_dst2, h2, al_s2, al_d2);
    agg2_kernel<<<NNODES / 4, 256, 0, stream>>>(h2, al_s2, al_d2, offs, csrsrc, b2, out);
}

// Round 12
// 365.259 us; speedup vs baseline: 2.1849x; 1.0029x over previous
//
#include <hip/hip_runtime.h>
#include <math.h>

#define NNODES 50000
#define FIN 512
#define HID 64
#define HEADS 4
#define HD (HEADS * HID)   // 256
#define NCLS 40
#define NCLSP 64           // padded to 4x16 MFMA n-tiles; pow2 for 8-lane-per-edge agg2
#define NEG_SLOPE 0.2f
#define SBLK 256
#define NSCAN ((NNODES + SBLK - 1) / SBLK)   // 196

#define W1TBLK (FIN * HD / 256)              // 512
#define W2TBLK NCLSP                         // 64

typedef __attribute__((ext_vector_type(8))) short short8;
typedef __attribute__((ext_vector_type(4))) float f32x4;

static __device__ inline unsigned short f2bf(float f) {
    unsigned int u = __builtin_bit_cast(unsigned int, f);
    unsigned int r = (u + 0x7FFFu + ((u >> 16) & 1u)) >> 16;
    return (unsigned short)r;
}
static __device__ inline float bf2f(unsigned short b) {
    return __builtin_bit_cast(float, (unsigned int)b << 16);
}
static __device__ inline void gload_lds16(const void* g, void* l) {
    __builtin_amdgcn_global_load_lds(
        (const __attribute__((address_space(1))) unsigned int*)g,
        (__attribute__((address_space(3))) unsigned int*)l, 16, 0, 0);
}

// ---------------- preprocess: deg count (+edge rank) + csr pad + W1t + W2t ---
// rank[e] = this edge's arrival index among its dst's edges (free byproduct
// of the degree atomic) -> scatter needs no cursor and no second atomic.
__global__ __launch_bounds__(256) void pre_kernel(const float* __restrict__ W1,
                                                  unsigned short* __restrict__ W1t,
                                                  const float* __restrict__ W2,
                                                  unsigned short* __restrict__ W2t,
                                                  const int* __restrict__ ei, int E, int eb,
                                                  int* __restrict__ deg,
                                                  int* __restrict__ rank,
                                                  int* __restrict__ csr_pad) {
    const int b = blockIdx.x;
    const int tid = threadIdx.x;
    if (b < eb) {
        const int e = b * 256 + tid;
        if (e < E) rank[e] = atomicAdd(&deg[ei[E + e]], 1);
        if (b == 0 && tid < 64) csr_pad[tid] = 0;   // safe pad for clamp-free agg loops
    } else if (b < eb + W1TBLK) {
        // W1[512,256] fp32 -> W1t[256,512] bf16
        const int idx = (b - eb) * 256 + tid;
        const int k = idx >> 8;
        const int n = idx & 255;
        W1t[n * FIN + k] = f2bf(W1[idx]);
    } else {
        // W2[256,40] fp32 -> W2t[64][256] bf16, rows 40..63 zero
        const int idx = (b - eb - W1TBLK) * 256 + tid;
        const int n = idx >> 8;
        const int k = idx & 255;
        W2t[n * HD + k] = (n < NCLS) ? f2bf(W2[k * NCLS + n]) : (unsigned short)0;
    }
}

// ---------------- GEMM1: BM=128 BN=256 BK=32, 8 waves, all-DMA staging -------
// BM 64->128: 2x MFMA per block at same per-wave LDS cost, half the barriers
// per output, half the per-output B-stage traffic. Wave (wr,wc)=(w>>2,w&3);
// wc's 64-col slice == head wc, so the fused score-dot epilogue is unchanged.
// A staged as fp32 via global_load_lds with chunk-XOR swizzle (rule #21:
// linear dest + inverse-swizzled source + swizzled read). 64 KB LDS.
#define BM 128
#define BN 256
#define BK 32
#define G1BLK ((NNODES + BM - 1) / BM)   // 391

__global__ __launch_bounds__(512) void gemm1_kernel(const float* __restrict__ x,
                                                    const unsigned short* __restrict__ W1t,
                                                    const float* __restrict__ a_src,
                                                    const float* __restrict__ a_dst,
                                                    unsigned short* __restrict__ h1,
                                                    float* __restrict__ al_s,
                                                    float* __restrict__ al_d) {
    __shared__ float As32[2][BM * BK];         // 2 x 16 KB [row][32 fp32] (swizzled chunks)
    __shared__ unsigned short Bs[2][BN * BK];  // 2 x 16 KB [n][k] bf16
    const int tid = threadIdx.x;
    const int wave = tid >> 6;           // 0..7
    const int wr = wave >> 2;            // output row half (0/1)
    const int wc = wave & 3;             // output col slice == head
    const int lane = tid & 63;
    const int quad = lane >> 4;
    const int col = lane & 15;
    const int m0 = blockIdx.x * BM;
    const int srow = lane >> 2;          // 0..15 within a 16-row group
    const int skk = (lane & 3) * 8;      // 8-elem bf16 (16B) k-chunk
    const int l3 = lane >> 3;            // row within 8-row group
    const int ch = lane & 7;             // stored 16B chunk within 128B row
    const int chs = ch ^ l3;             // swizzled source chunk (row&7 == l3)

    f32x4 acc[4][4] = {};

    auto stageA = [&](int buf, int k0) {
        #pragma unroll
        for (int j = 0; j < 2; ++j) {
            const int row = wave * 16 + j * 8 + l3;              // 0..127
            const size_t rg = (size_t)min(m0 + row, NNODES - 1) * FIN;  // clamped
            gload_lds16(&x[rg + k0 + chs * 4], &As32[buf][row * BK + ch * 4]);
        }
    };
    auto stageB = [&](int buf, int k0) {
        #pragma unroll
        for (int c = 0; c < 2; ++c) {
            const int rr = c * 128 + wave * 16 + srow;           // 0..255
            gload_lds16(&W1t[(size_t)rr * FIN + k0 + skk], &Bs[buf][rr * BK + skk]);
        }
    };
    auto compute = [&](int buf) {
        const int r7 = col & 7;          // (wr*64 + i*16 + col)&7 for all i
        short8 af[4], bfv[4];
        #pragma unroll
        for (int i = 0; i < 4; ++i) {
            const int row = wr * 64 + i * 16 + col;
            const float4 f0 = *(const float4*)&As32[buf][row * BK + (((2 * quad)     ^ r7) << 2)];
            const float4 f1 = *(const float4*)&As32[buf][row * BK + (((2 * quad + 1) ^ r7) << 2)];
            short8 p;
            p[0] = (short)f2bf(f0.x); p[1] = (short)f2bf(f0.y);
            p[2] = (short)f2bf(f0.z); p[3] = (short)f2bf(f0.w);
            p[4] = (short)f2bf(f1.x); p[5] = (short)f2bf(f1.y);
            p[6] = (short)f2bf(f1.z); p[7] = (short)f2bf(f1.w);
            af[i] = p;
        }
        #pragma unroll
        for (int j = 0; j < 4; ++j)
            bfv[j] = *(const short8*)&Bs[buf][(wc * 64 + j * 16 + col) * BK + quad * 8];
        #pragma unroll
        for (int i = 0; i < 4; ++i)
            #pragma unroll
            for (int j = 0; j < 4; ++j)
                acc[i][j] = __builtin_amdgcn_mfma_f32_16x16x32_bf16(af[i], bfv[j], acc[i][j], 0, 0, 0);
    };

    stageA(0, 0);
    stageB(0, 0);
    __syncthreads();
    int cur = 0;
    for (int k0 = BK; k0 < FIN; k0 += BK) {
        stageA(cur ^ 1, k0);   // async DMAs fly under compute, drain at barrier
        stageB(cur ^ 1, k0);
        compute(cur);
        __syncthreads();
        cur ^= 1;
    }
    compute(cur);

    // epilogue: h1 write + fused per-head attention score dots (head == wc)
    float asv[4], adv[4];
    #pragma unroll
    for (int j = 0; j < 4; ++j) {
        asv[j] = a_src[wc * 64 + j * 16 + col];
        adv[j] = a_dst[wc * 64 + j * 16 + col];
    }
    #pragma unroll
    for (int i = 0; i < 4; ++i) {
        #pragma unroll
        for (int reg = 0; reg < 4; ++reg) {
            const int row = wr * 64 + i * 16 + quad * 4 + reg;
            const int gm = m0 + row;
            float ds = 0.f, dd = 0.f;
            #pragma unroll
            for (int j = 0; j < 4; ++j) {
                const float v = acc[i][j][reg];
                ds = fmaf(v, asv[j], ds);
                dd = fmaf(v, adv[j], dd);
                if (gm < NNODES) {
                    const int gc = wc * 64 + j * 16 + col;
                    h1[(size_t)gm * HD + gc] = f2bf(v);
                }
            }
            #pragma unroll
            for (int off = 1; off < 16; off <<= 1) {
                ds += __shfl_xor(ds, off);
                dd += __shfl_xor(dd, off);
            }
            if (col == 0 && gm < NNODES) {
                al_s[gm * HEADS + wc] = ds;
                al_d[gm * HEADS + wc] = dd;
            }
        }
    }
}

// ---------------- CSR build: scans ------------------------------------------
__global__ __launch_bounds__(SBLK) void scan1_kernel(const int* __restrict__ deg,
                                                     int* __restrict__ psum,
                                                     int* __restrict__ bsum) {
    __shared__ int ws[4];
    const int t = threadIdx.x;
    const int idx = blockIdx.x * SBLK + t;
    const int lane = t & 63;
    const int w = t >> 6;
    int sv = (idx < NNODES) ? deg[idx] : 0;
    #pragma unroll
    for (int off = 1; off < 64; off <<= 1) {
        const int n = __shfl_up(sv, off);
        if (lane >= off) sv += n;
    }
    if (lane == 63) ws[w] = sv;
    __syncthreads();
    int add = 0;
    for (int i = 0; i < w; ++i) add += ws[i];
    sv += add;
    if (idx < NNODES) psum[idx] = sv;
    if (t == SBLK - 1) bsum[blockIdx.x] = sv;
}

__global__ __launch_bounds__(SBLK) void scan23_kernel(const int* __restrict__ deg,
                                                      const int* __restrict__ psum,
                                                      const int* __restrict__ bsum,
                                                      int* __restrict__ offsets) {
    __shared__ int ws[4];
    __shared__ int sc[NSCAN];
    const int t = threadIdx.x;
    const int lane = t & 63;
    const int w = t >> 6;
    int sv = (t < NSCAN) ? bsum[t] : 0;
    #pragma unroll
    for (int off = 1; off < 64; off <<= 1) {
        const int n = __shfl_up(sv, off);
        if (lane >= off) sv += n;
    }
    if (lane == 63) ws[w] = sv;
    __syncthreads();
    int add = 0;
    for (int i = 0; i < w; ++i) add += ws[i];
    sv += add;
    if (t < NSCAN) sc[t] = sv;
    __syncthreads();
    const int idx = blockIdx.x * SBLK + t;
    const int boff = (blockIdx.x > 0) ? sc[blockIdx.x - 1] : 0;
    if (idx < NNODES) offsets[idx] = psum[idx] - deg[idx] + boff;
    if (blockIdx.x == 0 && t == 0) offsets[NNODES] = sc[NSCAN - 1];
}

// scatter without atomics: pos = offs[dst] + rank[e] (rank from deg pass)
__global__ void scatter_kernel(const int* __restrict__ ei, int E,
                               const int* __restrict__ offsets,
                               const int* __restrict__ rank,
                               int* __restrict__ csr_src) {
    const int e = blockIdx.x * 256 + threadIdx.x;
    if (e < E) {
        const int dst = ei[E + e];
        const int src = ei[e];
        csr_src[offsets[dst] + rank[e]] = src;
    }
}

// ---------------- layer-1 aggregation: quarter-wave-per-edge, 4 streams ------
// (R6/R9 proven form — at the random-line L2-fill wall)
__global__ __launch_bounds__(256) void agg1_kernel(const unsigned short* __restrict__ h1,
                                                   const float* __restrict__ al_s,
                                                   const float* __restrict__ al_d,
                                                   const int* __restrict__ offsets,
                                                   const int* __restrict__ csr_src,
                                                   const float* __restrict__ b1,
                                                   unsigned short* __restrict__ h_act) {
    const int node = (blockIdx.x * 256 + threadIdx.x) >> 6;
    const int lane = threadIdx.x & 63;
    const int q = lane >> 4;         // edge stream 0..3
    const int fl = lane & 15;        // feature group: feats fl*16 .. fl*16+15
    const int h = fl >> 2;           // head for this feature group
    const float ad = al_d[node * HEADS + h];
    const int start = offsets[node];
    const int end = offsets[node + 1];

    float s = 0.f;
    float acc[16] = {};

    {
        const int idx = start + q;
        const int src0 = csr_src[idx];
        float sc = (idx < end) ? al_s[src0 * HEADS + h] : -__builtin_inff();
        uint4 v0 = *(const uint4*)&h1[(size_t)src0 * HD + fl * 16];
        uint4 v1 = *(const uint4*)&h1[(size_t)src0 * HD + fl * 16 + 8];

        for (int i = start; i < end; i += 4) {
            const int j = i + 4 + q;
            const int nsrc = csr_src[j];
            const float nsc = (j < end) ? al_s[nsrc * HEADS + h] : -__builtin_inff();
            const uint4 nv0 = *(const uint4*)&h1[(size_t)nsrc * HD + fl * 16];
            const uint4 nv1 = *(const uint4*)&h1[(size_t)nsrc * HD + fl * 16 + 8];
            float e_ = sc + ad;
            e_ = e_ > 0.f ? e_ : NEG_SLOPE * e_;
            const float p = __expf(e_);
            s += p;
            const unsigned int w[8] = {v0.x, v0.y, v0.z, v0.w, v1.x, v1.y, v1.z, v1.w};
            #pragma unroll
            for (int d = 0; d < 8; ++d) {
                const float lo = __builtin_bit_cast(float, w[d] << 16);
                const float hi = __builtin_bit_cast(float, w[d] & 0xFFFF0000u);
                acc[2 * d]     = fmaf(p, lo, acc[2 * d]);
                acc[2 * d + 1] = fmaf(p, hi, acc[2 * d + 1]);
            }
            sc = nsc; v0 = nv0; v1 = nv1;
        }
    }
    s += __shfl_xor(s, 16);
    s += __shfl_xor(s, 32);
    #pragma unroll
    for (int k = 0; k < 16; ++k) {
        acc[k] += __shfl_xor(acc[k], 16);
        acc[k] += __shfl_xor(acc[k], 32);
    }

    if (q == 0) {
        const float inv = 1.f / (s + 1e-16f);
        float bb[16];
        *(float4*)&bb[0]  = *(const float4*)&b1[fl * 16];
        *(float4*)&bb[4]  = *(const float4*)&b1[fl * 16 + 4];
        *(float4*)&bb[8]  = *(const float4*)&b1[fl * 16 + 8];
        *(float4*)&bb[12] = *(const float4*)&b1[fl * 16 + 12];
        short8 ob0, ob1;
        #pragma unroll
        for (int k = 0; k < 8; ++k) {
            const float o0 = acc[k] * inv + bb[k];
            const float o1 = acc[8 + k] * inv + bb[8 + k];
            const float e0 = o0 > 0.f ? o0 : expm1f(o0);
            const float e1 = o1 > 0.f ? o1 : expm1f(o1);
            ob0[k] = (short)f2bf(e0);
            ob1[k] = (short)f2bf(e1);
        }
        *(short8*)&h_act[(size_t)node * HD + fl * 16] = ob0;
        *(short8*)&h_act[(size_t)node * HD + fl * 16 + 8] = ob1;
    }
}

// ---------------- GEMM2 via MFMA: h2[N,64] = h_act[N,256] @ W2pad + dots -----
#define G2M 64
#define BSTRIDE 264

__global__ __launch_bounds__(256) void gemm2_kernel(const unsigned short* __restrict__ h_act,
                                                    const unsigned short* __restrict__ W2t,
                                                    const float* __restrict__ a_s2,
                                                    const float* __restrict__ a_d2,
                                                    unsigned short* __restrict__ h2,
                                                    float* __restrict__ al_s,
                                                    float* __restrict__ al_d) {
    __shared__ unsigned short Bt[NCLSP][BSTRIDE];
    const int tid = threadIdx.x;
    const int wave = tid >> 6;
    const int lane = tid & 63;
    const int quad = lane >> 4;
    const int col = lane & 15;
    const int m0 = blockIdx.x * G2M;

    #pragma unroll
    for (int it = 0; it < 8; ++it) {
        const int ch = it * 256 + tid;
        const int n = ch >> 5;
        const int c8 = (ch & 31) * 8;
        *(uint4*)&Bt[n][c8] = *(const uint4*)&W2t[(size_t)n * HD + c8];
    }

    const int rowm = m0 + wave * 16 + col;
    const int arow = min(rowm, NNODES - 1);
    short8 af[8];
    #pragma unroll
    for (int ks = 0; ks < 8; ++ks)
        af[ks] = *(const short8*)&h_act[(size_t)arow * HD + ks * 32 + quad * 8];

    __syncthreads();

    f32x4 acc[4] = {};
    #pragma unroll
    for (int j = 0; j < 4; ++j) {
        #pragma unroll
        for (int ks = 0; ks < 8; ++ks) {
            const short8 bfr = *(const short8*)&Bt[j * 16 + col][ks * 32 + quad * 8];
            acc[j] = __builtin_amdgcn_mfma_f32_16x16x32_bf16(af[ks], bfr, acc[j], 0, 0, 0);
        }
    }

    float ps[4] = {0.f, 0.f, 0.f, 0.f};
    float pd[4] = {0.f, 0.f, 0.f, 0.f};
    #pragma unroll
    for (int j = 0; j < 4; ++j) {
        const int c = j * 16 + col;
        const bool cv = c < NCLS;
        const float asc = cv ? a_s2[c] : 0.f;
        const float adc = cv ? a_d2[c] : 0.f;
        #pragma unroll
        for (int reg = 0; reg < 4; ++reg) {
            const float v = acc[j][reg];
            ps[reg] += v * asc;
            pd[reg] += v * adc;
            const int node = m0 + wave * 16 + quad * 4 + reg;
            if (node < NNODES)
                h2[(size_t)node * NCLSP + c] = f2bf(v);
        }
    }
    #pragma unroll
    for (int reg = 0; reg < 4; ++reg) {
        #pragma unroll
        for (int off = 1; off < 16; off <<= 1) {
            ps[reg] += __shfl_xor(ps[reg], off);
            pd[reg] += __shfl_xor(pd[reg], off);
        }
    }
    if (col == 0) {
        #pragma unroll
        for (int reg = 0; reg < 4; ++reg) {
            const int node = m0 + wave * 16 + quad * 4 + reg;
            if (node < NNODES) {
                al_s[node] = ps[reg];
                al_d[node] = pd[reg];
            }
        }
    }
}

// ---------------- layer-2 aggregation: octet-per-edge, 8 streams -------------
__global__ __launch_bounds__(256) void agg2_kernel(const unsigned short* __restrict__ h2,
                                                   const float* __restrict__ al_s,
                                                   const float* __restrict__ al_d,
                                                   const int* __restrict__ offsets,
                                                   const int* __restrict__ csr_src,
                                                   const float* __restrict__ b2,
                                                   float* __restrict__ out) {
    const int node = (blockIdx.x * 256 + threadIdx.x) >> 6;
    const int lane = threadIdx.x & 63;
    const int oct = lane >> 3;
    const int fl = lane & 7;
    const float ad = al_d[node];
    const int start = offsets[node];
    const int end = offsets[node + 1];

    float s = 0.f;
    float acc[8] = {};

    {
        const int idx = start + oct;
        const int src0 = csr_src[idx];
        float sc = (idx < end) ? al_s[src0] : -__builtin_inff();
        short8 v = *(const short8*)&h2[(size_t)src0 * NCLSP + fl * 8];

        for (int i = start; i < end; i += 8) {
            const int j = i + 8 + oct;
            const int nsrc = csr_src[j];
            const float nsc = (j < end) ? al_s[nsrc] : -__builtin_inff();
            const short8 nv = *(const short8*)&h2[(size_t)nsrc * NCLSP + fl * 8];
            float e_ = sc + ad;
            e_ = e_ > 0.f ? e_ : NEG_SLOPE * e_;
            const float p = __expf(e_);
            s += p;
            #pragma unroll
            for (int k = 0; k < 8; ++k)
                acc[k] = fmaf(p, bf2f((unsigned short)v[k]), acc[k]);
            sc = nsc; v = nv;
        }
    }
    s += __shfl_xor(s, 8);
    s += __shfl_xor(s, 16);
    s += __shfl_xor(s, 32);
    #pragma unroll
    for (int k = 0; k < 8; ++k) {
        acc[k] += __shfl_xor(acc[k], 8);
        acc[k] += __shfl_xor(acc[k], 16);
        acc[k] += __shfl_xor(acc[k], 32);
    }

    if (oct == 0) {
        const float inv = 1.f / (s + 1e-16f);
        float o[8];
        float mx = -1e30f;
        #pragma unroll
        for (int k = 0; k < 8; ++k) {
            const int c = fl * 8 + k;
            const float bc = (c < NCLS) ? b2[c] : 0.f;
            o[k] = acc[k] * inv + bc;
            if (c < NCLS) mx = fmaxf(mx, o[k]);
        }
        #pragma unroll
        for (int off = 1; off < 8; off <<= 1) mx = fmaxf(mx, __shfl_xor(mx, off));
        float ex = 0.f;
        #pragma unroll
        for (int k = 0; k < 8; ++k) {
            const int c = fl * 8 + k;
            if (c < NCLS) ex += __expf(o[k] - mx);
        }
        #pragma unroll
        for (int off = 1; off < 8; off <<= 1) ex += __shfl_xor(ex, off);
        const float lse = mx + logf(ex);
        if (fl < 5) {
            float4 r0, r1;
            r0.x = o[0] - lse; r0.y = o[1] - lse; r0.z = o[2] - lse; r0.w = o[3] - lse;
            r1.x = o[4] - lse; r1.y = o[5] - lse; r1.z = o[6] - lse; r1.w = o[7] - lse;
            *(float4*)&out[(size_t)node * NCLS + fl * 8] = r0;
            *(float4*)&out[(size_t)node * NCLS + fl * 8 + 4] = r1;
        }
    }
}

// ---------------- launch: 9 dispatches (R10 proven) --------------------------
extern "C" void kernel_launch(void* const* d_in, const int* in_sizes, int n_in,
                              void* d_out, int out_size, void* d_ws, size_t ws_size,
                              hipStream_t stream) {
    const float* x      = (const float*)d_in[0];
    const int*   ei     = (const int*)d_in[1];
    const float* W1     = (const float*)d_in[2];
    const float* a_src1 = (const float*)d_in[3];
    const float* a_dst1 = (const float*)d_in[4];
    const float* b1     = (const float*)d_in[5];
    const float* W2     = (const float*)d_in[6];
    const float* a_src2 = (const float*)d_in[7];
    const float* a_dst2 = (const float*)d_in[8];
    const float* b2     = (const float*)d_in[9];
    float* out = (float*)d_out;
    const int E = in_sizes[1] / 2;

    char* ws = (char*)d_ws;
    size_t off = 0;
    auto alloc = [&](size_t bytes) -> char* {
        char* p = ws + off;
        off += (bytes + 255) & ~(size_t)255;
        return p;
    };
    unsigned short* W1t   = (unsigned short*)alloc((size_t)FIN * HD * 2);
    unsigned short* W2t   = (unsigned short*)alloc((size_t)NCLSP * HD * 2);
    unsigned short* h1    = (unsigned short*)alloc((size_t)NNODES * HD * 2);
    unsigned short* h_act = (unsigned short*)alloc((size_t)NNODES * HD * 2);
    unsigned short* h2    = (unsigned short*)alloc((size_t)NNODES * NCLSP * 2);
    float* al_s1  = (float*)alloc((size_t)NNODES * HEADS * 4);
    float* al_d1  = (float*)alloc((size_t)NNODES * HEADS * 4);
    float* al_s2  = (float*)alloc((size_t)NNODES * 4);
    float* al_d2  = (float*)alloc((size_t)NNODES * 4);
    int*   deg    = (int*)alloc((size_t)NNODES * 4);
    int*   rank   = (int*)alloc((size_t)E * 4);
    int*   psum   = (int*)alloc((size_t)NNODES * 4);
    int*   bsum   = (int*)alloc((size_t)SBLK * 4);
    int*   offs   = (int*)alloc((size_t)(NNODES + 1) * 4);
    int*   csrsrc = (int*)alloc((size_t)E * 4 + 256);  // +64 safe pad entries

    hipMemsetAsync(deg, 0, (size_t)NNODES * 4, stream);

    const int eb = (E + 255) / 256;
    pre_kernel<<<eb + W1TBLK + W2TBLK, 256, 0, stream>>>(W1, W1t, W2, W2t, ei, E, eb, deg, rank, csrsrc + E);
    scan1_kernel<<<NSCAN, SBLK, 0, stream>>>(deg, psum, bsum);
    scan23_kernel<<<NSCAN, SBLK, 0, stream>>>(deg, psum, bsum, offs);
    scatter_kernel<<<eb, 256, 0, stream>>>(ei, E, offs, rank, csrsrc);

    gemm1_kernel<<<G1BLK, 512, 0, stream>>>(x, W1t, a_src1, a_dst1, h1, al_s1, al_d1);
    agg1_kernel<<<NNODES / 4, 256, 0, stream>>>(h1, al_s1, al_d1, offs, csrsrc, b1, h_act);
    gemm2_kernel<<<(NNODES + G2M - 1) / G2M, 256, 0, stream>>>(h_act, W2t, a_src2, a_dst2, h2, al_s2, al_d2);
    agg2_kernel<<<NNODES / 4, 256, 0, stream>>>(h2, al_s2, al_d2, offs, csrsrc, b2, out);
}